// Round 5
// baseline (86.117 us; speedup 1.0000x reference)
//
#include <hip/hip_runtime.h>

// Problem constants (from reference): NY,NX,NZ,C = 496,432,1,64; N=320000; B=4
#define NY_ 496
#define NX_ 432
#define NZ_ 1
#define C_ 64
#define NVOX_ 320000
#define BATCH_ 4
#define SPATIAL_ (NY_ * NX_ * NZ_)        // 214272 cells per batch (mult of 4)
#define NCELLS_ (BATCH_ * SPATIAL_)       // 857088 total cells (mult of 1024)

typedef float f32x4 __attribute__((ext_vector_type(4)));
typedef int   i32x4 __attribute__((ext_vector_type(4)));

// K1: init winner table (in d_ws) to -1, vectorized 16B
__global__ void gs_init_winner(i32x4* __restrict__ winner4) {
    int j = blockIdx.x * blockDim.x + threadIdx.x;   // NCELLS_/4 = 214272 threads
    i32x4 v = {-1, -1, -1, -1};
    winner4[j] = v;
}

// K2: vote — last write wins == max voxel index wins (numpy fancy-assign semantics)
__global__ void gs_vote(const int* __restrict__ coors, int* __restrict__ winner) {
    int i = blockIdx.x * blockDim.x + threadIdx.x;
    if (i >= NVOX_) return;
    i32x4 czyx = *reinterpret_cast<const i32x4*>(coors + 4 * i); // [b, z, y, x]
    int b = czyx.x, z = czyx.y, y = czyx.z, x = czyx.w;
    int cell = ((b * NY_ + y) * NX_ + x) * NZ_ + z;
    atomicMax(&winner[cell], i);
}

// K3: output-centric fill. One thread per 4 consecutive cells. Two channel-half
// passes; row-major 128 B contiguous loads per winner row, 4x4 register
// transpose, PLAIN f32x4 stores (16 B/lane, 1 KB contiguous per wave-instr).
// R5 change vs R4: removed __builtin_nontemporal_store (A/B test — harness
// memset hits 7 TB/s with plain stores; NT may defeat L2 write-combining).
__global__ void gs_fill(const float* __restrict__ vf,
                        const int* __restrict__ winner,
                        float* __restrict__ out) {
    int t = blockIdx.x * blockDim.x + threadIdx.x;   // NCELLS_/4 threads
    int cell0 = t * 4;
    int b  = cell0 / SPATIAL_;
    int sp = cell0 - b * SPATIAL_;

    i32x4 w = *reinterpret_cast<const i32x4*>(winner + cell0);
    float m0 = (w.x >= 0) ? 1.0f : 0.0f;  int i0 = (w.x >= 0) ? w.x : 0;
    float m1 = (w.y >= 0) ? 1.0f : 0.0f;  int i1 = (w.y >= 0) ? w.y : 0;
    float m2 = (w.z >= 0) ? 1.0f : 0.0f;  int i2 = (w.z >= 0) ? w.z : 0;
    float m3 = (w.w >= 0) ? 1.0f : 0.0f;  int i3 = (w.w >= 0) ? w.w : 0;

    const f32x4* r0 = reinterpret_cast<const f32x4*>(vf + (size_t)i0 * C_);
    const f32x4* r1 = reinterpret_cast<const f32x4*>(vf + (size_t)i1 * C_);
    const f32x4* r2 = reinterpret_cast<const f32x4*>(vf + (size_t)i2 * C_);
    const f32x4* r3 = reinterpret_cast<const f32x4*>(vf + (size_t)i3 * C_);

    float* outp = out + (size_t)b * C_ * SPATIAL_ + sp;

#pragma unroll
    for (int half = 0; half < 2; ++half) {
        int q0 = half * 8;
        f32x4 d0[8], d1[8], d2[8], d3[8];
        // Load phase: row-major, 128 B contiguous per row
#pragma unroll
        for (int q = 0; q < 8; ++q) d0[q] = r0[q0 + q];
#pragma unroll
        for (int q = 0; q < 8; ++q) d1[q] = r1[q0 + q];
#pragma unroll
        for (int q = 0; q < 8; ++q) d2[q] = r2[q0 + q];
#pragma unroll
        for (int q = 0; q < 8; ++q) d3[q] = r3[q0 + q];
        // Store phase: quad-major 4x4 transpose + plain stores
#pragma unroll
        for (int q = 0; q < 8; ++q) {
            int c = (q0 + q) * 4;
            f32x4 a = d0[q], bb = d1[q], cc = d2[q], dd = d3[q];
            f32x4 o0 = {a.x * m0, bb.x * m1, cc.x * m2, dd.x * m3};
            f32x4 o1 = {a.y * m0, bb.y * m1, cc.y * m2, dd.y * m3};
            f32x4 o2 = {a.z * m0, bb.z * m1, cc.z * m2, dd.z * m3};
            f32x4 o3 = {a.w * m0, bb.w * m1, cc.w * m2, dd.w * m3};
            *reinterpret_cast<f32x4*>(outp + (size_t)(c + 0) * SPATIAL_) = o0;
            *reinterpret_cast<f32x4*>(outp + (size_t)(c + 1) * SPATIAL_) = o1;
            *reinterpret_cast<f32x4*>(outp + (size_t)(c + 2) * SPATIAL_) = o2;
            *reinterpret_cast<f32x4*>(outp + (size_t)(c + 3) * SPATIAL_) = o3;
        }
    }
}

extern "C" void kernel_launch(void* const* d_in, const int* in_sizes, int n_in,
                              void* d_out, int out_size, void* d_ws, size_t ws_size,
                              hipStream_t stream) {
    const float* vf    = (const float*)d_in[0];  // (N, C) float32
    const int*   coors = (const int*)d_in[1];    // (N, 4) int32 [b,z,y,x]
    // d_in[2] = batch_size scalar (fixed at 4, baked into constants)
    float* out  = (float*)d_out;                 // (B, C, NY, NX, NZ) float32
    int* winner = (int*)d_ws;                    // NCELLS_ ints = 3.43 MB scratch

    gs_init_winner<<<NCELLS_ / 4 / 256, 256, 0, stream>>>((i32x4*)winner); // 837 blocks
    gs_vote<<<(NVOX_ + 255) / 256, 256, 0, stream>>>(coors, winner);
    gs_fill<<<NCELLS_ / 4 / 256, 256, 0, stream>>>(vf, winner, out);       // 837 blocks
}

// Round 6
// 69.773 us; speedup vs baseline: 1.2343x; 1.2343x over previous
//
#include <hip/hip_runtime.h>

// Problem constants (from reference): NY,NX,NZ,C = 496,432,1,64; N=320000; B=4
#define NY_ 496
#define NX_ 432
#define NZ_ 1
#define C_ 64
#define NVOX_ 320000
#define BATCH_ 4
#define SPATIAL_ (NY_ * NX_ * NZ_)        // 214272 cells per batch (mult of 4)
#define NCELLS_ (BATCH_ * SPATIAL_)       // 857088 total cells (mult of 1024)

typedef float f32x4 __attribute__((ext_vector_type(4)));
typedef int   i32x4 __attribute__((ext_vector_type(4)));

// K1: init winner table (in d_ws) to -1, vectorized 16B
__global__ void gs_init_winner(i32x4* __restrict__ winner4) {
    int j = blockIdx.x * blockDim.x + threadIdx.x;   // NCELLS_/4 = 214272 threads
    i32x4 v = {-1, -1, -1, -1};
    winner4[j] = v;
}

// K2: vote — last write wins == max voxel index wins (numpy fancy-assign semantics)
__global__ void gs_vote(const int* __restrict__ coors, int* __restrict__ winner) {
    int i = blockIdx.x * blockDim.x + threadIdx.x;
    if (i >= NVOX_) return;
    i32x4 czyx = *reinterpret_cast<const i32x4*>(coors + 4 * i); // [b, z, y, x]
    int b = czyx.x, z = czyx.y, y = czyx.z, x = czyx.w;
    int cell = ((b * NY_ + y) * NX_ + x) * NZ_ + z;
    atomicMax(&winner[cell], i);
}

// K3: output-centric fill. One thread per 4 consecutive cells. Row-major 128 B
// contiguous loads per winner row, 4x4 register transpose, NT f32x4 stores
// (16 B/lane, 1 KB contiguous per wave-instr; NT bypasses L2 so the 219 MB
// write stream doesn't evict the gathered vf rows — R5 A/B: plain stores +11us).
// R6 change vs R4: 64-thread blocks (3348 blocks, ~13/CU) to kill the 837-block
// scheduling-quantization tail (3.27 blocks/CU -> 69 CUs ran a 4th block).
__global__ void __launch_bounds__(64)
gs_fill(const float* __restrict__ vf,
        const int* __restrict__ winner,
        float* __restrict__ out) {
    int t = blockIdx.x * blockDim.x + threadIdx.x;   // NCELLS_/4 threads
    int cell0 = t * 4;
    int b  = cell0 / SPATIAL_;
    int sp = cell0 - b * SPATIAL_;

    i32x4 w = *reinterpret_cast<const i32x4*>(winner + cell0);
    float m0 = (w.x >= 0) ? 1.0f : 0.0f;  int i0 = (w.x >= 0) ? w.x : 0;
    float m1 = (w.y >= 0) ? 1.0f : 0.0f;  int i1 = (w.y >= 0) ? w.y : 0;
    float m2 = (w.z >= 0) ? 1.0f : 0.0f;  int i2 = (w.z >= 0) ? w.z : 0;
    float m3 = (w.w >= 0) ? 1.0f : 0.0f;  int i3 = (w.w >= 0) ? w.w : 0;

    const f32x4* r0 = reinterpret_cast<const f32x4*>(vf + (size_t)i0 * C_);
    const f32x4* r1 = reinterpret_cast<const f32x4*>(vf + (size_t)i1 * C_);
    const f32x4* r2 = reinterpret_cast<const f32x4*>(vf + (size_t)i2 * C_);
    const f32x4* r3 = reinterpret_cast<const f32x4*>(vf + (size_t)i3 * C_);

    float* outp = out + (size_t)b * C_ * SPATIAL_ + sp;

#pragma unroll
    for (int half = 0; half < 2; ++half) {
        int q0 = half * 8;
        f32x4 d0[8], d1[8], d2[8], d3[8];
        // Load phase: row-major, 128 B contiguous per row
#pragma unroll
        for (int q = 0; q < 8; ++q) d0[q] = r0[q0 + q];
#pragma unroll
        for (int q = 0; q < 8; ++q) d1[q] = r1[q0 + q];
#pragma unroll
        for (int q = 0; q < 8; ++q) d2[q] = r2[q0 + q];
#pragma unroll
        for (int q = 0; q < 8; ++q) d3[q] = r3[q0 + q];
        // Store phase: quad-major 4x4 transpose + NT stores
#pragma unroll
        for (int q = 0; q < 8; ++q) {
            int c = (q0 + q) * 4;
            f32x4 a = d0[q], bb = d1[q], cc = d2[q], dd = d3[q];
            f32x4 o0 = {a.x * m0, bb.x * m1, cc.x * m2, dd.x * m3};
            f32x4 o1 = {a.y * m0, bb.y * m1, cc.y * m2, dd.y * m3};
            f32x4 o2 = {a.z * m0, bb.z * m1, cc.z * m2, dd.z * m3};
            f32x4 o3 = {a.w * m0, bb.w * m1, cc.w * m2, dd.w * m3};
            __builtin_nontemporal_store(o0, reinterpret_cast<f32x4*>(outp + (size_t)(c + 0) * SPATIAL_));
            __builtin_nontemporal_store(o1, reinterpret_cast<f32x4*>(outp + (size_t)(c + 1) * SPATIAL_));
            __builtin_nontemporal_store(o2, reinterpret_cast<f32x4*>(outp + (size_t)(c + 2) * SPATIAL_));
            __builtin_nontemporal_store(o3, reinterpret_cast<f32x4*>(outp + (size_t)(c + 3) * SPATIAL_));
        }
    }
}

extern "C" void kernel_launch(void* const* d_in, const int* in_sizes, int n_in,
                              void* d_out, int out_size, void* d_ws, size_t ws_size,
                              hipStream_t stream) {
    const float* vf    = (const float*)d_in[0];  // (N, C) float32
    const int*   coors = (const int*)d_in[1];    // (N, 4) int32 [b,z,y,x]
    // d_in[2] = batch_size scalar (fixed at 4, baked into constants)
    float* out  = (float*)d_out;                 // (B, C, NY, NX, NZ) float32
    int* winner = (int*)d_ws;                    // NCELLS_ ints = 3.43 MB scratch

    gs_init_winner<<<NCELLS_ / 4 / 256, 256, 0, stream>>>((i32x4*)winner); // 837 blocks
    gs_vote<<<(NVOX_ + 255) / 256, 256, 0, stream>>>(coors, winner);
    gs_fill<<<NCELLS_ / 4 / 64, 64, 0, stream>>>(vf, winner, out);         // 3348 blocks
}